// Round 1
// baseline (130.078 us; speedup 1.0000x reference)
//
#include <hip/hip_runtime.h>

#define BB 8
#define CC 19
#define HH 256
#define WW 256
#define INFD 1e6f
#define IT 4

// ws layout:
// [0, 32)            : has_b int[8]  (zeroed each launch)
// [256, 256+2MB)     : g2   [B,H,W] float (squared row distance)
// [256+2MB, 256+4MB) : wmap [B,H,W] float (boundary weight)

__global__ __launch_bounds__(256) void k_boundary_rowdist(
    const int* __restrict__ tgt, float* __restrict__ g2, int* __restrict__ has_b)
{
    __shared__ int trow[3][WW];
    __shared__ int bflag[WW];
    __shared__ int s_any;
    const int b = blockIdx.x >> 8;
    const int h = blockIdx.x & 255;
    const int j = threadIdx.x;
    const int hm = max(h - 1, 0), hp = min(h + 1, HH - 1);
    const int* base = tgt + b * HH * WW;
    trow[0][j] = base[hm * WW + j];
    trow[1][j] = base[h  * WW + j];
    trow[2][j] = base[hp * WW + j];
    if (j == 0) s_any = 0;
    __syncthreads();

    const int jm = max(j - 1, 0), jp = min(j + 1, WW - 1);
    int mx = trow[0][jm], mn = trow[0][jm];
#pragma unroll
    for (int r = 0; r < 3; ++r) {
        int a0 = trow[r][jm], a1 = trow[r][j], a2 = trow[r][jp];
        mx = max(mx, max(a0, max(a1, a2)));
        mn = min(mn, min(a0, min(a1, a2)));
    }
    const int bnd = (mx != mn) ? 1 : 0;
    bflag[j] = bnd;
    unsigned long long msk = __ballot(bnd);
    if ((threadIdx.x & 63) == 0 && msk) s_any = 1;   // idempotent LDS store
    __syncthreads();
    if (j == 0 && s_any) has_b[b] = 1;               // idempotent global store

    // expanding search for nearest boundary in this row (dense boundaries -> ~1 iter)
    float mind = INFD;
    for (int d = 0; d < WW; ++d) {
        int lo = j - d, hi = j + d;
        bool hit = (lo >= 0 && bflag[lo]) || (hi < WW && bflag[hi]);
        if (hit) { mind = (float)d; break; }
    }
    g2[(b * HH + h) * WW + j] = mind * mind;   // 1e6^2 = 1e12 matches reference INF**2
}

__global__ __launch_bounds__(256) void k_edt(
    const float* __restrict__ g2, const int* __restrict__ has_b,
    float* __restrict__ wmap)
{
    const int b  = blockIdx.x / (HH / IT);
    const int it = blockIdx.x % (HH / IT);
    const int i0 = it * IT;
    const int j  = threadIdx.x;
    const int has = has_b[b];

    float md[IT];
#pragma unroll
    for (int r = 0; r < IT; ++r) md[r] = 3e12f;

    const float* gcol = g2 + (size_t)b * HH * WW + j;
    for (int k = 0; k < HH; ++k) {
        float g = gcol[(size_t)k * WW];           // coalesced across j
#pragma unroll
        for (int r = 0; r < IT; ++r) {
            float dk = (float)(i0 + r - k);       // dk^2 exact in fp32 (<=255^2)
            md[r] = fminf(md[r], fmaf(dk, dk, g));
        }
    }
#pragma unroll
    for (int r = 0; r < IT; ++r) {
        float dist = sqrtf(md[r]);
        float w = has ? expf(-dist / 5.0f) : 1.0f;
        wmap[((size_t)b * HH + i0 + r) * WW + j] = w;
    }
}

__global__ __launch_bounds__(256) void k_ce_reduce(
    const float* __restrict__ x, const int* __restrict__ tgt,
    const float* __restrict__ wmap, float* __restrict__ out)
{
    const int gid = blockIdx.x * 256 + threadIdx.x;   // [0, B*H*W)
    const int b   = gid >> 16;                        // H*W = 65536
    const int pix = gid & 65535;
    const float* px = x + (size_t)b * CC * HH * WW + pix;

    float m = -1e30f;
    float v[CC];
#pragma unroll
    for (int c = 0; c < CC; ++c) {
        v[c] = px[(size_t)c * HH * WW];               // coalesced across pix
        m = fmaxf(m, v[c]);
    }
    float s = 0.0f;
#pragma unroll
    for (int c = 0; c < CC; ++c) s += expf(v[c] - m);
    const float lse = m + logf(s);

    const int t = tgt[gid];
    const float xt = px[(size_t)t * HH * WW];         // re-load (L1/L2 hot) to avoid
                                                      // dynamic-indexed register array
    float acc = (lse - xt) * wmap[gid];

    // wave64 shuffle reduce
    for (int off = 32; off > 0; off >>= 1)
        acc += __shfl_down(acc, off, 64);
    __shared__ float wsum[4];
    const int lane = threadIdx.x & 63, wid = threadIdx.x >> 6;
    if (lane == 0) wsum[wid] = acc;
    __syncthreads();
    if (threadIdx.x == 0) {
        float tot = wsum[0] + wsum[1] + wsum[2] + wsum[3];
        atomicAdd(out, tot * (1.0f / (float)(BB * HH * WW)));
    }
}

extern "C" void kernel_launch(void* const* d_in, const int* in_sizes, int n_in,
                              void* d_out, int out_size, void* d_ws, size_t ws_size,
                              hipStream_t stream) {
    const float* x   = (const float*)d_in[0];
    const int*   tgt = (const int*)d_in[1];
    float*       out = (float*)d_out;

    char* ws = (char*)d_ws;
    int*   has_b = (int*)ws;
    float* g2    = (float*)(ws + 256);
    float* wmap  = (float*)(ws + 256 + (size_t)BB * HH * WW * sizeof(float));

    hipMemsetAsync(ws, 0, 256, stream);
    hipMemsetAsync(d_out, 0, sizeof(float), stream);

    k_boundary_rowdist<<<BB * HH, 256, 0, stream>>>(tgt, g2, has_b);
    k_edt<<<BB * (HH / IT), 256, 0, stream>>>(g2, has_b, wmap);
    k_ce_reduce<<<(BB * HH * WW) / 256, 256, 0, stream>>>(x, tgt, wmap, out);
}

// Round 2
// 112.382 us; speedup vs baseline: 1.1575x; 1.1575x over previous
//
#include <hip/hip_runtime.h>

#define BB 8
#define CC 19
#define HH 256
#define WW 256
#define HWW 65536   // H*W
#define INFD 1e6f
#define IT 8        // rows per k_edt block

// ws layout:
// [0, 2MB)        : g2     [B,H,W] float  (squared row distance)
// [2MB, 4MB)      : wmap   [B,H,W] float  (boundary weight)
// [4MB, 4MB+8KB)  : rowany int[B*H]       (per-row boundary flag, plain-stored)

__global__ __launch_bounds__(256) void k_bnd(
    const int* __restrict__ tgt, float* __restrict__ g2,
    int* __restrict__ rowany, float* __restrict__ out)
{
    __shared__ int trow[3][WW];
    __shared__ int bflag[WW];
    __shared__ int s_any;
    const int b = blockIdx.x >> 8;
    const int h = blockIdx.x & 255;
    const int j = threadIdx.x;
    if (blockIdx.x == 0 && j == 0) out[0] = 0.0f;   // zero accumulator (runs before k_ce)
    const int hm = max(h - 1, 0), hp = min(h + 1, HH - 1);
    const int* base = tgt + b * HWW;
    trow[0][j] = base[hm * WW + j];
    trow[1][j] = base[h  * WW + j];
    trow[2][j] = base[hp * WW + j];
    if (j == 0) s_any = 0;
    __syncthreads();

    const int jm = max(j - 1, 0), jp = min(j + 1, WW - 1);
    int mx = trow[0][jm], mn = trow[0][jm];
#pragma unroll
    for (int r = 0; r < 3; ++r) {
        int a0 = trow[r][jm], a1 = trow[r][j], a2 = trow[r][jp];
        mx = max(mx, max(a0, max(a1, a2)));
        mn = min(mn, min(a0, min(a1, a2)));
    }
    const int bnd = (mx != mn) ? 1 : 0;
    bflag[j] = bnd;
    unsigned long long msk = __ballot(bnd);
    if ((j & 63) == 0 && msk) s_any = 1;            // idempotent LDS store
    __syncthreads();
    if (j == 0) rowany[blockIdx.x] = s_any;         // plain store, no init needed

    // expanding search for nearest boundary in this row (dense boundaries -> ~1 iter)
    float mind = INFD;
    for (int d = 0; d < WW; ++d) {
        int lo = j - d, hi = j + d;
        bool hit = (lo >= 0 && bflag[lo]) || (hi < WW && bflag[hi]);
        if (hit) { mind = (float)d; break; }
    }
    g2[(b * HH + h) * WW + j] = mind * mind;        // 1e6^2 = 1e12 matches reference INF**2
}

__global__ __launch_bounds__(256) void k_edt(
    const float* __restrict__ g2, const int* __restrict__ rowany,
    float* __restrict__ wmap)
{
    const int b  = blockIdx.x >> 5;                 // 32 blocks per image (256/IT)
    const int i0 = (blockIdx.x & 31) * IT;
    const int j  = threadIdx.x;

    __shared__ int s_has;
    if (j == 0) s_has = 0;
    const int ra = rowany[b * HH + j];              // one coalesced load of 256 flags
    unsigned long long mk = __ballot(ra != 0);
    __syncthreads();
    if ((j & 63) == 0 && mk) s_has = 1;
    __syncthreads();
    const int has = s_has;

    float md[IT];
#pragma unroll
    for (int r = 0; r < IT; ++r) md[r] = 3e12f;

    const float* gcol = g2 + (size_t)b * HWW + j;
#pragma unroll 4
    for (int k = 0; k < HH; ++k) {
        float g = gcol[(size_t)k * WW];             // coalesced across j
#pragma unroll
        for (int r = 0; r < IT; ++r) {
            float dk = (float)(i0 + r - k);         // dk^2 exact in fp32 (<=255^2)
            md[r] = fminf(md[r], fmaf(dk, dk, g));
        }
    }
#pragma unroll
    for (int r = 0; r < IT; ++r) {
        float dist = sqrtf(md[r]);
        float w = has ? expf(-dist / 5.0f) : 1.0f;
        wmap[((size_t)b * HH + i0 + r) * WW + j] = w;
    }
}

__global__ __launch_bounds__(256) void k_ce(
    const float* __restrict__ x, const int* __restrict__ tgt,
    const float* __restrict__ wmap, float* __restrict__ out)
{
    const int q   = blockIdx.x * 256 + threadIdx.x; // quad index [0, B*H*W/4)
    const int p0  = q << 2;                         // first pixel of the quad
    const int b   = p0 >> 16;                       // H*W = 65536
    const int pix = p0 & 65535;
    const float* px = x + (size_t)b * CC * HWW + pix;

    float4 v[CC];
    float4 m = make_float4(-1e30f, -1e30f, -1e30f, -1e30f);
#pragma unroll
    for (int c = 0; c < CC; ++c) {
        v[c] = *(const float4*)(px + (size_t)c * HWW);   // 16B coalesced
        m.x = fmaxf(m.x, v[c].x); m.y = fmaxf(m.y, v[c].y);
        m.z = fmaxf(m.z, v[c].z); m.w = fmaxf(m.w, v[c].w);
    }
    float4 s = make_float4(0.f, 0.f, 0.f, 0.f);
#pragma unroll
    for (int c = 0; c < CC; ++c) {
        s.x += expf(v[c].x - m.x); s.y += expf(v[c].y - m.y);
        s.z += expf(v[c].z - m.z); s.w += expf(v[c].w - m.w);
    }
    const float lse0 = m.x + logf(s.x), lse1 = m.y + logf(s.y);
    const float lse2 = m.z + logf(s.z), lse3 = m.w + logf(s.w);

    const int4  t = *(const int4*)(tgt + p0);
    const float xt0 = px[(size_t)t.x * HWW + 0];    // gather, L1/L2 hot
    const float xt1 = px[(size_t)t.y * HWW + 1];
    const float xt2 = px[(size_t)t.z * HWW + 2];
    const float xt3 = px[(size_t)t.w * HWW + 3];
    const float4 w = *(const float4*)(wmap + p0);

    float acc = (lse0 - xt0) * w.x + (lse1 - xt1) * w.y
              + (lse2 - xt2) * w.z + (lse3 - xt3) * w.w;

    // wave64 shuffle reduce
    for (int off = 32; off > 0; off >>= 1)
        acc += __shfl_down(acc, off, 64);
    __shared__ float wsum[4];
    const int lane = threadIdx.x & 63, wid = threadIdx.x >> 6;
    if (lane == 0) wsum[wid] = acc;
    __syncthreads();
    if (threadIdx.x == 0) {
        float tot = wsum[0] + wsum[1] + wsum[2] + wsum[3];
        atomicAdd(out, tot * (1.0f / (float)(BB * HWW)));
    }
}

extern "C" void kernel_launch(void* const* d_in, const int* in_sizes, int n_in,
                              void* d_out, int out_size, void* d_ws, size_t ws_size,
                              hipStream_t stream) {
    const float* x   = (const float*)d_in[0];
    const int*   tgt = (const int*)d_in[1];
    float*       out = (float*)d_out;

    char* ws = (char*)d_ws;
    float* g2     = (float*)ws;
    float* wmap   = (float*)(ws + (size_t)BB * HWW * sizeof(float));
    int*   rowany = (int*)  (ws + (size_t)2 * BB * HWW * sizeof(float));

    k_bnd<<<BB * HH, 256, 0, stream>>>(tgt, g2, rowany, out);
    k_edt<<<BB * (HH / IT), 256, 0, stream>>>(g2, rowany, wmap);
    k_ce <<<(BB * HWW / 4) / 256, 256, 0, stream>>>(x, tgt, wmap, out);
}

// Round 3
// 98.716 us; speedup vs baseline: 1.3177x; 1.1384x over previous
//
#include <hip/hip_runtime.h>

#define BB 8
#define CC 19
#define HH 256
#define WW 256
#define HWW 65536   // H*W
#define INFD 1e6f
#define IT 8        // rows per k_edt block

// ws layout:
// [0, 2MB)        : g2     [B,H,W] float  (squared row distance)
// [2MB, 4MB)      : ce     [B,H,W] float  (unweighted cross-entropy)
// [4MB, 4MB+8KB)  : rowany int[B*H]       (per-row boundary flag, plain-stored)

__global__ __launch_bounds__(256) void k_bnd_ce(
    const float* __restrict__ x, const int* __restrict__ tgt,
    float* __restrict__ g2, float* __restrict__ ce,
    int* __restrict__ rowany, float* __restrict__ out)
{
    __shared__ int trow[3][WW];
    __shared__ int bflag[WW];
    __shared__ int s_any;
    const int b = blockIdx.x >> 8;
    const int h = blockIdx.x & 255;
    const int j = threadIdx.x;
    if (blockIdx.x == 0 && j == 0) out[0] = 0.0f;   // zero accumulator (k_edt runs after)
    const int hm = max(h - 1, 0), hp = min(h + 1, HH - 1);
    const int* tbase = tgt + b * HWW;
    trow[0][j] = tbase[hm * WW + j];
    trow[1][j] = tbase[h  * WW + j];
    trow[2][j] = tbase[hp * WW + j];
    if (j == 0) s_any = 0;
    __syncthreads();

    // --- boundary (3x3 morphological gradient, edge padding) ---
    const int jm = max(j - 1, 0), jp = min(j + 1, WW - 1);
    int mx = trow[0][jm], mn = trow[0][jm];
#pragma unroll
    for (int r = 0; r < 3; ++r) {
        int a0 = trow[r][jm], a1 = trow[r][j], a2 = trow[r][jp];
        mx = max(mx, max(a0, max(a1, a2)));
        mn = min(mn, min(a0, min(a1, a2)));
    }
    const int bnd = (mx != mn) ? 1 : 0;
    bflag[j] = bnd;
    unsigned long long msk = __ballot(bnd);
    if ((j & 63) == 0 && msk) s_any = 1;            // idempotent LDS store
    __syncthreads();
    if (j == 0) rowany[blockIdx.x] = s_any;         // plain store, no init needed

    // --- per-row 1D distance (expanding search; dense boundaries -> ~1 iter) ---
    float mind = INFD;
    for (int d = 0; d < WW; ++d) {
        int lo = j - d, hi = j + d;
        bool hit = (lo >= 0 && bflag[lo]) || (hi < WW && bflag[hi]);
        if (hit) { mind = (float)d; break; }
    }
    g2[(b * HH + h) * WW + j] = mind * mind;        // 1e6^2 = 1e12 matches reference INF**2

    // --- unweighted cross-entropy for this pixel (the 40 MB stream) ---
    const float* px = x + ((size_t)(b * CC) * HH + h) * WW + j;
    float v[CC];
    float m = -1e30f;
#pragma unroll
    for (int c = 0; c < CC; ++c) {
        v[c] = px[(size_t)c * HWW];                 // coalesced dword across j
        m = fmaxf(m, v[c]);
    }
    float s = 0.0f;
#pragma unroll
    for (int c = 0; c < CC; ++c) s += expf(v[c] - m);
    const float lse = m + logf(s);
    const int t = trow[1][j];                       // target already in LDS
    const float xt = px[(size_t)t * HWW];           // L1-hot reload (avoid dyn reg index)
    ce[(b * HH + h) * WW + j] = lse - xt;
}

__global__ __launch_bounds__(256) void k_edt_red(
    const float* __restrict__ g2, const float* __restrict__ ce,
    const int* __restrict__ rowany, float* __restrict__ out)
{
    const int b  = blockIdx.x >> 5;                 // 32 blocks per image (256/IT)
    const int i0 = (blockIdx.x & 31) * IT;
    const int j  = threadIdx.x;

    __shared__ int s_has;
    if (j == 0) s_has = 0;
    const int ra = rowany[b * HH + j];              // one coalesced load of 256 flags
    unsigned long long mk = __ballot(ra != 0);
    __syncthreads();
    if ((j & 63) == 0 && mk) s_has = 1;
    __syncthreads();
    const int has = s_has;

    float md[IT];
#pragma unroll
    for (int r = 0; r < IT; ++r) md[r] = 3e12f;

    const float* gcol = g2 + (size_t)b * HWW + j;
#pragma unroll 8
    for (int k = 0; k < HH; ++k) {
        float g = gcol[(size_t)k * WW];             // coalesced across j, L2-hot
#pragma unroll
        for (int r = 0; r < IT; ++r) {
            float dk = (float)(i0 + r - k);         // dk^2 exact in fp32 (<=255^2)
            md[r] = fminf(md[r], fmaf(dk, dk, g));
        }
    }

    float acc = 0.0f;
#pragma unroll
    for (int r = 0; r < IT; ++r) {
        float dist = sqrtf(md[r]);
        float w = has ? expf(-dist / 5.0f) : 1.0f;
        acc += ce[((size_t)b * HH + i0 + r) * WW + j] * w;
    }

    // wave64 shuffle reduce
    for (int off = 32; off > 0; off >>= 1)
        acc += __shfl_down(acc, off, 64);
    __shared__ float wsum[4];
    const int lane = threadIdx.x & 63, wid = threadIdx.x >> 6;
    if (lane == 0) wsum[wid] = acc;
    __syncthreads();
    if (threadIdx.x == 0) {
        float tot = wsum[0] + wsum[1] + wsum[2] + wsum[3];
        atomicAdd(out, tot * (1.0f / (float)(BB * HWW)));
    }
}

extern "C" void kernel_launch(void* const* d_in, const int* in_sizes, int n_in,
                              void* d_out, int out_size, void* d_ws, size_t ws_size,
                              hipStream_t stream) {
    const float* x   = (const float*)d_in[0];
    const int*   tgt = (const int*)d_in[1];
    float*       out = (float*)d_out;

    char* ws = (char*)d_ws;
    float* g2     = (float*)ws;
    float* ce     = (float*)(ws + (size_t)BB * HWW * sizeof(float));
    int*   rowany = (int*)  (ws + (size_t)2 * BB * HWW * sizeof(float));

    k_bnd_ce <<<BB * HH, 256, 0, stream>>>(x, tgt, g2, ce, rowany, out);
    k_edt_red<<<BB * (HH / IT), 256, 0, stream>>>(g2, ce, rowany, out);
}